// Round 1
// baseline (85170.428 us; speedup 1.0000x reference)
//
#include <hip/hip_runtime.h>
#include <cstddef>

#define NB 32
#define SS 1024
#define WIN 1024
#define EE 128
#define HH 512

__device__ __forceinline__ float sigm(float x) { return 1.f / (1.f + __expf(-x)); }
__device__ __forceinline__ float tanh_(float x) { return 1.f - 2.f / (__expf(2.f * x) + 1.f); }

// 16-wide fp32 dot block: accumulates into a0..a3 (declared by caller)
#define DOT16(wp, hp, kk) do { \
    float4 w0_ = *(const float4*)((wp) + (kk));      float4 x0_ = *(const float4*)((hp) + (kk)); \
    float4 w1_ = *(const float4*)((wp) + (kk) + 4);  float4 x1_ = *(const float4*)((hp) + (kk) + 4); \
    float4 w2_ = *(const float4*)((wp) + (kk) + 8);  float4 x2_ = *(const float4*)((hp) + (kk) + 8); \
    float4 w3_ = *(const float4*)((wp) + (kk) + 12); float4 x3_ = *(const float4*)((hp) + (kk) + 12); \
    a0 = fmaf(w0_.x, x0_.x, a0); a0 = fmaf(w0_.y, x0_.y, a0); a0 = fmaf(w0_.z, x0_.z, a0); a0 = fmaf(w0_.w, x0_.w, a0); \
    a1 = fmaf(w1_.x, x1_.x, a1); a1 = fmaf(w1_.y, x1_.y, a1); a1 = fmaf(w1_.z, x1_.z, a1); a1 = fmaf(w1_.w, x1_.w, a1); \
    a2 = fmaf(w2_.x, x2_.x, a2); a2 = fmaf(w2_.y, x2_.y, a2); a2 = fmaf(w2_.z, x2_.z, a2); a2 = fmaf(w2_.w, x2_.w, a2); \
    a3 = fmaf(w3_.x, x3_.x, a3); a3 = fmaf(w3_.y, x3_.y, a3); a3 = fmaf(w3_.z, x3_.z, a3); a3 = fmaf(w3_.w, x3_.w, a3); \
  } while (0)

// ---------------- K1: embed = relu(inputs @ W_e^T + b_e), layout [s][b][e] ----------------
__global__ __launch_bounds__(256) void k_embed(
    const float* __restrict__ inp, const float* __restrict__ We,
    const float* __restrict__ be, float* __restrict__ emb)
{
  __shared__ float sA[32 * 68];    // [kk][m] transposed
  __shared__ float sW[32 * 132];   // [kk][e]
  const int tid = threadIdx.x;
  const int b  = blockIdx.x >> 4;
  const int s0 = (blockIdx.x & 15) << 6;
  float acc[4][8];
#pragma unroll
  for (int i = 0; i < 4; ++i)
#pragma unroll
    for (int j = 0; j < 8; ++j) acc[i][j] = 0.f;
  const int m4 = (tid & 15) << 2;
  const int e8 = (tid >> 4) << 3;
  const float* Ab = inp + ((size_t)(b << 10) + s0) * 1024;
  const int ms = tid >> 2, kq = tid & 3;
  const int es = tid >> 1, kq2 = tid & 1;
  for (int k0 = 0; k0 < 1024; k0 += 32) {
    __syncthreads();
    {
      const float* src = Ab + (size_t)ms * 1024 + k0 + (kq << 3);
      float4 v0 = *(const float4*)(src);
      float4 v1 = *(const float4*)(src + 4);
      int kb = kq << 3;
      sA[(kb+0)*68+ms] = v0.x; sA[(kb+1)*68+ms] = v0.y;
      sA[(kb+2)*68+ms] = v0.z; sA[(kb+3)*68+ms] = v0.w;
      sA[(kb+4)*68+ms] = v1.x; sA[(kb+5)*68+ms] = v1.y;
      sA[(kb+6)*68+ms] = v1.z; sA[(kb+7)*68+ms] = v1.w;
    }
    {
      const float* src = We + (size_t)es * 1024 + k0 + (kq2 << 4);
#pragma unroll
      for (int q = 0; q < 4; ++q) {
        float4 v = *(const float4*)(src + (q << 2));
        int kb = (kq2 << 4) + (q << 2);
        sW[(kb+0)*132+es] = v.x; sW[(kb+1)*132+es] = v.y;
        sW[(kb+2)*132+es] = v.z; sW[(kb+3)*132+es] = v.w;
      }
    }
    __syncthreads();
#pragma unroll 4
    for (int kk = 0; kk < 32; ++kk) {
      float4 a4 = *(const float4*)&sA[kk*68 + m4];
      float4 b0 = *(const float4*)&sW[kk*132 + e8];
      float4 b1 = *(const float4*)&sW[kk*132 + e8 + 4];
      float av[4] = {a4.x, a4.y, a4.z, a4.w};
      float bv[8] = {b0.x, b0.y, b0.z, b0.w, b1.x, b1.y, b1.z, b1.w};
#pragma unroll
      for (int i = 0; i < 4; ++i)
#pragma unroll
        for (int j = 0; j < 8; ++j) acc[i][j] = fmaf(av[i], bv[j], acc[i][j]);
    }
  }
#pragma unroll
  for (int i = 0; i < 4; ++i) {
    int s = s0 + m4 + i;
#pragma unroll
    for (int j = 0; j < 8; ++j) {
      float v = acc[i][j] + be[e8 + j];
      emb[((size_t)(s << 5) + b) * 128 + e8 + j] = v > 0.f ? v : 0.f;
    }
  }
}

// ---------------- K2: a = relu(embed @ Wa1^T + ba1) @ Wa2^T + ba2, layout [s*32+b][3] ----------------
__global__ __launch_bounds__(256) void k_attn(
    const float* __restrict__ emb, const float* __restrict__ Wa1,
    const float* __restrict__ ba1, const float* __restrict__ Wa2,
    const float* __restrict__ ba2, float* __restrict__ aw)
{
  __shared__ float sE[2 * 128];
  __shared__ float sH[2 * 128];
  const int tid = threadIdx.x;
  const int rs0 = blockIdx.x * 2;
  sE[tid] = emb[(size_t)rs0 * 128 + tid];
  __syncthreads();
  const int half = tid >> 7, j = tid & 127;
  const float* w = Wa1 + j * 128;
  const float* e = sE + half * 128;
  float a0 = 0.f, a1 = 0.f, a2 = 0.f, a3 = 0.f;
  for (int k = 0; k < 128; k += 16) DOT16(w, e, k);
  float h = (a0 + a1) + (a2 + a3) + ba1[j];
  sH[half * 128 + j] = h > 0.f ? h : 0.f;
  __syncthreads();
  if (tid < 6) {
    int hh = tid / 3, l = tid % 3;
    const float* w2 = Wa2 + l * 128;
    const float* hv = sH + hh * 128;
    float s = 0.f;
    for (int k = 0; k < 128; ++k) s = fmaf(w2[k], hv[k], s);
    aw[(size_t)(rs0 + hh) * 3 + l] = s + ba2[l];
  }
}

// ---------------- K2b: softmax over time (axis s) per (b, l), in-place ----------------
__global__ __launch_bounds__(256) void k_softmax(float* __restrict__ aw)
{
  __shared__ float red[256];
  const int b = blockIdx.x / 3, l = blockIdx.x % 3;
  const int tid = threadIdx.x;
  float v[4];
#pragma unroll
  for (int i = 0; i < 4; ++i) {
    int s = tid + i * 256;
    v[i] = aw[(size_t)(s * 32 + b) * 3 + l];
  }
  float mx = fmaxf(fmaxf(v[0], v[1]), fmaxf(v[2], v[3]));
  red[tid] = mx;
  __syncthreads();
  for (int off = 128; off > 0; off >>= 1) {
    if (tid < off) red[tid] = fmaxf(red[tid], red[tid + off]);
    __syncthreads();
  }
  mx = red[0];
  __syncthreads();
  float sm = 0.f;
#pragma unroll
  for (int i = 0; i < 4; ++i) sm += __expf(v[i] - mx);
  red[tid] = sm;
  __syncthreads();
  for (int off = 128; off > 0; off >>= 1) {
    if (tid < off) red[tid] += red[tid + off];
    __syncthreads();
  }
  float inv = 1.f / red[0];
#pragma unroll
  for (int i = 0; i < 4; ++i) {
    int s = tid + i * 256;
    aw[(size_t)(s * 32 + b) * 3 + l] = __expf(v[i] - mx) * inv;
  }
}

// ---------------- K_init: initial states + d_out = b_o2 ----------------
__global__ __launch_bounds__(256) void k_init(
    const float* __restrict__ eh0, const float* __restrict__ ec0,
    const float* __restrict__ dh0, const float* __restrict__ dc0,
    const float* __restrict__ bo2,
    float* __restrict__ heb, float* __restrict__ hdb,
    float* __restrict__ ceb, float* __restrict__ cdb, float* __restrict__ out)
{
  const int i = blockIdx.x * 256 + threadIdx.x;   // 32768 threads
  if (i < 16384) {
    int k = i & 511;
    heb[16384 + i] = eh0[k];   // slot 1 == slot for t=-1
    hdb[16384 + i] = dh0[k];
    ceb[i] = ec0[k];
    cdb[i] = dc0[k];
  }
  out[i] = bo2[0];
}

// ---------------- K_enc(t): out-duty(t-1) + encoder step t + context publish ----------------
// wg g owns enc h-indices {2g, 2g+1}; wgs 0..127 also own W_o1 row g.
__global__ __launch_bounds__(256) void k_enc(
    const int t,
    const float* __restrict__ emb, const float* __restrict__ aw,
    const int* __restrict__ lens,
    const float* __restrict__ Wih, const float* __restrict__ Whh,
    const float* __restrict__ bih, const float* __restrict__ bhh,
    const float* __restrict__ Wo1, const float* __restrict__ bo1,
    const float* __restrict__ Wo2,
    float* __restrict__ heb, float* __restrict__ ctxb,
    const float* __restrict__ hdb,
    float* __restrict__ ceb, float* __restrict__ hm, float* __restrict__ out)
{
  __shared__ float sW[8 * 520];     // Whh_e rows (pad 520)
  __shared__ float sWx[8 * 132];    // Wih_e rows (pad 132)
  __shared__ float sStg[32 * 520];  // h_e[t-1] staged [b][k]
  __shared__ float sX[32 * 132];    // embed[t] staged [b][e]
  __shared__ float sG[8 * 33];      // gate exchange
  __shared__ float sB[8];           // bias slice
  const int tid = threadIdx.x;
  const int g = blockIdx.x;
  const int j0 = g << 1;

  // ---- output-layer duty for step t-1 (wgs 0..127, one W_o1 row each) ----
  if (g < 128 && t > 0) {
    const int ks = tid & 7, b = tid >> 3;
    const float* hd = hdb + (size_t)((t + 1) & 1) * 16384 + b * 512 + ks * 64;
    const float* wo = Wo1 + (size_t)g * 512 + ks * 64;
    float a0 = 0.f, a1 = 0.f, a2 = 0.f, a3 = 0.f;
    for (int k = 0; k < 64; k += 16) DOT16(wo, hd, k);
    float s = (a0 + a1) + (a2 + a3);
    s += __shfl_down(s, 4, 8);
    s += __shfl_down(s, 2, 8);
    s += __shfl_down(s, 1, 8);
    if (ks == 0) {
      float q = s + bo1[g];
      q = q > 0.f ? q : 0.f;
      atomicAdd(&out[b * 1024 + (t - 1)], q * Wo2[g]);
    }
  }
  if (t >= 1024) return;

  // ---- stage weights + inputs ----
  for (int i = tid; i < 4096; i += 256) {
    int r = i >> 9, k = i & 511;
    int row = ((r >> 1) << 9) + j0 + (r & 1);
    sW[r * 520 + k] = Whh[(size_t)row * 512 + k];
  }
  for (int i = tid; i < 1024; i += 256) {
    int r = i >> 7, e = i & 127;
    int row = ((r >> 1) << 9) + j0 + (r & 1);
    sWx[r * 132 + e] = Wih[(size_t)row * 128 + e];
  }
  if (tid < 8) {
    int row = ((tid >> 1) << 9) + j0 + (tid & 1);
    sB[tid] = bih[row] + bhh[row];
  }
  {
    const float* src = heb + (size_t)((t + 1) & 1) * 16384;
    for (int i = tid * 4; i < 16384; i += 1024) {
      int b = i >> 9, k = i & 511;
      *(float4*)&sStg[b * 520 + k] = *(const float4*)&src[i];
    }
    const float* sx = emb + (size_t)t * 4096;
    for (int i = tid * 4; i < 4096; i += 1024) {
      int b = i >> 7, e = i & 127;
      *(float4*)&sX[b * 132 + e] = *(const float4*)&sx[i];
    }
  }
  __syncthreads();

  // ---- gate dots: thread = (row r, batch b) ----
  {
    const int r = tid & 7, b = tid >> 3;
    const float* wr = sW + r * 520;
    const float* hb = sStg + b * 520;
    float a0 = 0.f, a1 = 0.f, a2 = 0.f, a3 = 0.f;
    for (int k = 0; k < 512; k += 16) DOT16(wr, hb, k);
    const float* wx = sWx + r * 132;
    const float* xb = sX + b * 132;
    for (int k = 0; k < 128; k += 16) DOT16(wx, xb, k);
    sG[r * 33 + b] = (a0 + a1) + (a2 + a3) + sB[r];
  }
  __syncthreads();

  // ---- cell update + publish h_e, masked ring, context ----
  if (tid < 64) {
    const int jl = tid & 1, bb = tid >> 1;
    float gi = sG[(0 + jl) * 33 + bb];
    float gf = sG[(2 + jl) * 33 + bb];
    float gg = sG[(4 + jl) * 33 + bb];
    float go = sG[(6 + jl) * 33 + bb];
    const int ci = (bb << 9) + j0 + jl;
    float c = ceb[ci];
    c = sigm(gf) * c + sigm(gi) * tanh_(gg);
    float h = sigm(go) * tanh_(c);
    ceb[ci] = c;
    heb[(size_t)(t & 1) * 16384 + ci] = h;
    float hmv = (t < lens[bb]) ? h : 0.f;
    hm[(size_t)(t % 3) * 16384 + ci] = hmv;
    const float* at = aw + (size_t)(t * 32 + bb) * 3;
    float ctx = at[0] * hmv;
    if (t >= 1) ctx += at[1] * hm[(size_t)((t - 1) % 3) * 16384 + ci];
    if (t >= 2) ctx += at[2] * hm[(size_t)((t - 2) % 3) * 16384 + ci];
    ctxb[(size_t)(t & 1) * 16384 + ci] = ctx;
  }
}

// ---------------- K_dec(t): decoder step t ----------------
// sWd row layout: [0..511] = Wih_d[row][1..512] (ctx), [512..1023] = Whh_d[row], [1024] = Wih_d[row][0] (p)
__global__ __launch_bounds__(256) void k_dec(
    const int t,
    const float* __restrict__ Wih, const float* __restrict__ Whh,
    const float* __restrict__ bih, const float* __restrict__ bhh,
    const float* __restrict__ ctxb,
    float* __restrict__ hdb, float* __restrict__ cdb,
    const float* __restrict__ out)
{
  __shared__ float sWd[8 * 1032];
  __shared__ float sStg[32 * 520];
  __shared__ float sG[8 * 33];
  __shared__ float sB[8];
  const int tid = threadIdx.x;
  const int g = blockIdx.x;
  const int j0 = g << 1;

  for (int r = 0; r < 8; ++r) {
    int row = ((r >> 1) << 9) + j0 + (r & 1);
    const float* wi = Wih + (size_t)row * 513;
    const float* wh = Whh + (size_t)row * 512;
    for (int q = tid; q < 1025; q += 256) {
      float v;
      if (q < 512)       v = wi[1 + q];
      else if (q < 1024) v = wh[q - 512];
      else               v = wi[0];
      sWd[r * 1032 + q] = v;
    }
  }
  if (tid < 8) {
    int row = ((tid >> 1) << 9) + j0 + (tid & 1);
    sB[tid] = bih[row] + bhh[row];
  }
  {
    const float* src = hdb + (size_t)((t + 1) & 1) * 16384;
    for (int i = tid * 4; i < 16384; i += 1024) {
      int b = i >> 9, k = i & 511;
      *(float4*)&sStg[b * 520 + k] = *(const float4*)&src[i];
    }
  }
  __syncthreads();

  const int r = tid & 7, b = tid >> 3;
  float a0 = 0.f, a1 = 0.f, a2 = 0.f, a3 = 0.f;
  {
    const float* wh = sWd + r * 1032 + 512;
    const float* hb = sStg + b * 520;
    for (int k = 0; k < 512; k += 16) DOT16(wh, hb, k);
  }
  __syncthreads();  // done reading h stage
  {
    const float* src = ctxb + (size_t)(t & 1) * 16384;
    for (int i = tid * 4; i < 16384; i += 1024) {
      int bb = i >> 9, k = i & 511;
      *(float4*)&sStg[bb * 520 + k] = *(const float4*)&src[i];
    }
  }
  __syncthreads();
  {
    const float* wc = sWd + r * 1032;
    const float* cb = sStg + b * 520;
    for (int k = 0; k < 512; k += 16) DOT16(wc, cb, k);
  }
  float pv = (t == 0) ? 0.f : out[b * 1024 + (t - 1)];
  sG[r * 33 + b] = (a0 + a1) + (a2 + a3) + pv * sWd[r * 1032 + 1024] + sB[r];
  __syncthreads();

  if (tid < 64) {
    const int jl = tid & 1, bb = tid >> 1;
    float gi = sG[(0 + jl) * 33 + bb];
    float gf = sG[(2 + jl) * 33 + bb];
    float gg = sG[(4 + jl) * 33 + bb];
    float go = sG[(6 + jl) * 33 + bb];
    const int ci = (bb << 9) + j0 + jl;
    float c = cdb[ci];
    c = sigm(gf) * c + sigm(gi) * tanh_(gg);
    float h = sigm(go) * tanh_(c);
    cdb[ci] = c;
    hdb[(size_t)(t & 1) * 16384 + ci] = h;
  }
}

// ---------------- K_mask: predicted *= mask ----------------
__global__ __launch_bounds__(256) void k_mask(float* __restrict__ out, const float* __restrict__ mask)
{
  int i = blockIdx.x * 256 + threadIdx.x;
  out[i] *= mask[i];
}

extern "C" void kernel_launch(void* const* d_in, const int* in_sizes, int n_in,
                              void* d_out, int out_size, void* d_ws, size_t ws_size,
                              hipStream_t stream)
{
  const float* inp   = (const float*)d_in[0];
  const float* maskp = (const float*)d_in[1];
  const int*   lens  = (const int*)d_in[2];
  const float* We    = (const float*)d_in[3];
  const float* be    = (const float*)d_in[4];
  const float* Wa1   = (const float*)d_in[5];
  const float* ba1   = (const float*)d_in[6];
  const float* Wa2   = (const float*)d_in[7];
  const float* ba2   = (const float*)d_in[8];
  const float* Wih_e = (const float*)d_in[9];
  const float* Whh_e = (const float*)d_in[10];
  const float* bih_e = (const float*)d_in[11];
  const float* bhh_e = (const float*)d_in[12];
  const float* eh0   = (const float*)d_in[13];
  const float* ec0   = (const float*)d_in[14];
  const float* Wih_d = (const float*)d_in[15];
  const float* Whh_d = (const float*)d_in[16];
  const float* bih_d = (const float*)d_in[17];
  const float* bhh_d = (const float*)d_in[18];
  const float* dh0   = (const float*)d_in[19];
  const float* dc0   = (const float*)d_in[20];
  const float* Wo1   = (const float*)d_in[21];
  const float* bo1   = (const float*)d_in[22];
  const float* Wo2   = (const float*)d_in[23];
  const float* bo2   = (const float*)d_in[24];

  float* ws   = (float*)d_ws;
  float* emb  = ws;                  // 4,194,304 floats  [s][b][e]
  float* aw   = emb + 4194304;       //    98,304 floats  [s*32+b][3]
  float* heb  = aw + 98304;          //    32,768 floats  [2][b][h]
  float* ctxb = heb + 32768;         //    32,768
  float* hdb  = ctxb + 32768;        //    32,768
  float* ceb  = hdb + 32768;         //    16,384
  float* cdb  = ceb + 16384;         //    16,384
  float* hm   = cdb + 16384;         //    49,152  [3][b][h]
  float* outf = (float*)d_out;

  k_embed<<<512, 256, 0, stream>>>(inp, We, be, emb);
  k_attn<<<16384, 256, 0, stream>>>(emb, Wa1, ba1, Wa2, ba2, aw);
  k_softmax<<<96, 256, 0, stream>>>(aw);
  k_init<<<128, 256, 0, stream>>>(eh0, ec0, dh0, dc0, bo2, heb, hdb, ceb, cdb, outf);

  for (int t = 0; t < 1024; ++t) {
    k_enc<<<256, 256, 0, stream>>>(t, emb, aw, lens, Wih_e, Whh_e, bih_e, bhh_e,
                                   Wo1, bo1, Wo2, heb, ctxb, hdb, ceb, hm, outf);
    k_dec<<<256, 256, 0, stream>>>(t, Wih_d, Whh_d, bih_d, bhh_d, ctxb, hdb, cdb, outf);
  }
  // final output-layer duty for t=1023 (enc body skipped via t>=1024 guard)
  k_enc<<<256, 256, 0, stream>>>(1024, emb, aw, lens, Wih_e, Whh_e, bih_e, bhh_e,
                                 Wo1, bo1, Wo2, heb, ctxb, hdb, ceb, hm, outf);
  k_mask<<<128, 256, 0, stream>>>(outf, maskp);
}